// Round 4
// baseline (90.089 us; speedup 1.0000x reference)
//
#include <hip/hip_runtime.h>
#include <stdint.h>

#define BB   32
#define CC1  256
#define HH   56
#define WW   56
#define PH   57          // padded (top/left zero row+col)
#define OHH  28
#define OWW  28
#define NPIX (OHH*OWW)   // 784
#define CC2  512
#define EPSV 1e-5f

typedef unsigned short ushortx8 __attribute__((ext_vector_type(8)));

static __device__ __forceinline__ int popc64(uint64_t v) {
    return __builtin_popcountll(v);
}
static __device__ __forceinline__ unsigned short f2bf(float f) {
    uint32_t u = __float_as_uint(f);
    u += 0x7FFFu + ((u >> 16) & 1u);          // RNE
    return (unsigned short)(u >> 16);
}
static __device__ __forceinline__ float bf2f(unsigned short u) {
    return __uint_as_float(((uint32_t)u) << 16);
}

// ---------- pack sign(x) (padded) + 2x2 avgpool (bf16) + zero borders/hbits ----------
// One thread per (b, cg, pool-cell): reads 64 ch x 4 px of x ONCE, emits
// 4 sign words + 8 pooled bf16x8 chunks in conv3-friendly [b][g][p][8] layout.
__global__ __launch_bounds__(256) void k_binpool(const float* __restrict__ x,
                                                 uint64_t* __restrict__ xbp,
                                                 uint64_t* __restrict__ hbits,
                                                 unsigned short* __restrict__ pool) {
    int gid = blockIdx.x * 256 + threadIdx.x;         // 100352
    hbits[gid] = 0ull;                                // exactly BB*NPIX*4 words
    if (gid < 7296) {                                 // top padded row: 32*57*4
        int b = gid / 228, r = gid % 228;
        xbp[((size_t)(b * PH) * PH + (r >> 2)) * 4 + (r & 3)] = 0ull;
    } else if (gid < 14464) {                         // left padded col rows 1..56: 32*56*4
        int i = gid - 7296;
        int b = i / 224, r = i % 224;
        xbp[((size_t)(b * PH + (r >> 2) + 1) * PH) * 4 + (r & 3)] = 0ull;
    }

    int cell = gid % NPIX;
    int cg   = (gid / NPIX) & 3;                      // 0..3
    int b    = gid / (NPIX * 4);
    int pw = cell % OWW;
    int ph = cell / OWW;
    int h0 = 2 * ph, w0 = 2 * pw;
    const float* base = x + ((size_t)(b * CC1 + cg * 64)) * (HH * WW) + h0 * WW + w0;

    uint64_t s00 = 0, s01 = 0, s10 = 0, s11 = 0;
    for (int j = 0; j < 8; ++j) {
        ushortx8 pv;
        #pragma unroll
        for (int i = 0; i < 8; ++i) {
            int c = j * 8 + i;
            const float* cp = base + (size_t)c * (HH * WW);
            float2 a = *(const float2*)(cp);
            float2 d = *(const float2*)(cp + WW);
            s00 |= (uint64_t)(a.x >= 0.0f) << c;
            s01 |= (uint64_t)(a.y >= 0.0f) << c;
            s10 |= (uint64_t)(d.x >= 0.0f) << c;
            s11 |= (uint64_t)(d.y >= 0.0f) << c;
            pv[i] = f2bf(0.25f * (a.x + a.y + d.x + d.y));
        }
        *(ushortx8*)(pool + ((size_t)((b * 32 + cg * 8 + j) * NPIX + cell)) * 8) = pv;
    }

    size_t rb = ((size_t)(b * PH + h0 + 1) * PH + w0 + 1) * 4 + cg;
    xbp[rb]          = s00;
    xbp[rb + 4]      = s01;
    xbp[rb + PH * 4]     = s10;
    xbp[rb + PH * 4 + 4] = s11;
}

// ---------- pack sign(w3) into layout w3t[tap][oc][k] ----------
__global__ __launch_bounds__(256) void k_packw3(const float* __restrict__ w3,
                                                uint64_t* __restrict__ w3t) {
    int id = blockIdx.x * 256 + threadIdx.x;          // 9216
    int k   = id % 4;
    int tap = (id / 4) % 9;
    int oc  = id / 36;
    const float* wp = w3 + (size_t)oc * 2304 + (size_t)(k * 64) * 9 + tap;
    uint64_t bits = 0;
    #pragma unroll 8
    for (int c = 0; c < 64; ++c) {
        bits |= (uint64_t)(wp[c * 9] >= 0.0f) << c;
    }
    w3t[((size_t)tap * CC1 + oc) * 4 + k] = bits;
}

// ---------- pack sign(w1) + fold BN constants + padding corrections ----------
__global__ __launch_bounds__(256) void k_prep2(const float* __restrict__ w1,
                                               uint64_t* __restrict__ w1b,
                                               const uint64_t* __restrict__ w3t,
                                               const float* __restrict__ g3,
                                               const float* __restrict__ b3,
                                               const float* __restrict__ m3,
                                               const float* __restrict__ v3,
                                               const float* __restrict__ g1,
                                               const float* __restrict__ b1,
                                               const float* __restrict__ m1,
                                               const float* __restrict__ v1,
                                               float* __restrict__ sc3,
                                               float* __restrict__ bi3,
                                               float* __restrict__ sc1,
                                               float* __restrict__ bi1,
                                               int* __restrict__ ctop,
                                               int* __restrict__ cleft,
                                               int* __restrict__ ccorn) {
    int id = blockIdx.x * 256 + threadIdx.x;          // 2048
    int k  = id % 4;
    int oc = id / 4;
    const float* wp = w1 + (size_t)oc * 256 + k * 64;
    uint64_t bits = 0;
    #pragma unroll 8
    for (int c = 0; c < 64; ++c) {
        bits |= (uint64_t)(wp[c] >= 0.0f) << c;
    }
    w1b[(size_t)oc * 4 + k] = bits;
    if (k == 0) {
        float s1 = g1[oc] / sqrtf(v1[oc] + EPSV);
        sc1[oc] = s1;
        bi1[oc] = b1[oc] - m1[oc] * s1;
        if (oc < CC1) {
            float s3 = g3[oc] / sqrtf(v3[oc] + EPSV);
            sc3[oc] = s3;
            bi3[oc] = b3[oc] - m3[oc] * s3;
        }
    }
    if (id < CC1) {
        int pt[9];
        #pragma unroll
        for (int t = 0; t < 9; ++t) {
            const uint64_t* p = w3t + ((size_t)t * CC1 + id) * 4;
            pt[t] = popc64(p[0]) + popc64(p[1]) + popc64(p[2]) + popc64(p[3]);
        }
        ctop[id]  = (256 - 2 * pt[0]) + (256 - 2 * pt[1]) + (256 - 2 * pt[2]);
        cleft[id] = (256 - 2 * pt[0]) + (256 - 2 * pt[3]) + (256 - 2 * pt[6]);
        ccorn[id] = (256 - 2 * pt[0]);
    }
}

// ---------- 3x3 stride-2 binary conv + BN + pooled shortcut + sign-pack ----------
__global__ __launch_bounds__(256, 4) void k_conv3(const uint64_t* __restrict__ xbp,
                                                  const uint64_t* __restrict__ w3t,
                                                  const float* __restrict__ sc3,
                                                  const float* __restrict__ bi3,
                                                  const int* __restrict__ ctop,
                                                  const int* __restrict__ cleft,
                                                  const int* __restrict__ ccorn,
                                                  const unsigned short* __restrict__ pool,
                                                  unsigned short* __restrict__ hbuf,
                                                  uint64_t* __restrict__ hbits) {
    int loc = blockIdx.x * 256 + threadIdx.x;         // 25088
    int p  = loc % NPIX;
    int ow = p % OWW;
    int oh = p / OWW;
    int b  = loc / NPIX;
    int ocg = blockIdx.y;                             // 0..31, 8 oc each

    int tot[8] = {0, 0, 0, 0, 0, 0, 0, 0};
    for (int kh = 0; kh < 3; ++kh) {
        const uint64_t* rp = xbp + ((size_t)((b * PH + 2 * oh + kh) * PH) + 2 * ow) * 4;
        uint64_t t0[4], t1[4], t2[4];
        #pragma unroll
        for (int k = 0; k < 4; ++k) { t0[k] = rp[k]; t1[k] = rp[4 + k]; t2[k] = rp[8 + k]; }
        const uint64_t* wrow = w3t + ((size_t)(kh * 3) * CC1 + ocg * 8) * 4;
        #pragma unroll
        for (int o = 0; o < 8; ++o) {
            const uint64_t* w0  = wrow + (size_t)o * 4;
            const uint64_t* w1p = w0 + (size_t)CC1 * 4;
            const uint64_t* w2p = w0 + (size_t)CC1 * 8;
            int s = tot[o];
            #pragma unroll
            for (int k = 0; k < 4; ++k) s += popc64(t0[k] ^ w0[k]);
            #pragma unroll
            for (int k = 0; k < 4; ++k) s += popc64(t1[k] ^ w1p[k]);
            #pragma unroll
            for (int k = 0; k < 4; ++k) s += popc64(t2[k] ^ w2p[k]);
            tot[o] = s;
        }
    }

    ushortx8 pv = *(const ushortx8*)(pool + ((size_t)((b * 32 + ocg) * NPIX + p)) * 8);

    bool top  = (oh == 0);
    bool left = (ow == 0);
    uint64_t hb = 0;
    #pragma unroll
    for (int o = 0; o < 8; ++o) {
        int oc = ocg * 8 + o;
        int corr = (top ? ctop[oc] : 0) + (left ? cleft[oc] : 0)
                 - ((top && left) ? ccorn[oc] : 0);
        float y = (float)(2304 - 2 * tot[o] - corr);
        float hv = y * sc3[oc] + bi3[oc] + bf2f(pv[o]);
        hbuf[((size_t)(b * CC1 + oc)) * NPIX + p] = f2bf(hv);
        hb |= (uint64_t)(hv >= 0.0f) << ((ocg & 7) * 8 + o);
    }
    atomicOr((unsigned long long*)&hbits[(size_t)loc * 4 + (ocg >> 3)],
             (unsigned long long)hb);
}

// ---------- 1x1 binary conv + BN + concat(h,h) shortcut ----------
__global__ __launch_bounds__(256, 4) void k_conv1(const uint64_t* __restrict__ hbits,
                                                  const uint64_t* __restrict__ w1b,
                                                  const unsigned short* __restrict__ hbuf,
                                                  const float* __restrict__ sc1,
                                                  const float* __restrict__ bi1,
                                                  float* __restrict__ out) {
    int loc = blockIdx.x * 256 + threadIdx.x;         // 25088
    int p = loc % NPIX;
    int b = loc / NPIX;
    int ocg = blockIdx.y;                             // 0..31, 8 channel-pairs

    uint64_t hw[4];
    const uint64_t* hp = hbits + (size_t)loc * 4;
    #pragma unroll
    for (int k = 0; k < 4; ++k) hw[k] = hp[k];

    #pragma unroll
    for (int o = 0; o < 8; ++o) {
        int oc  = ocg * 8 + o;          // 0..255
        int oc2 = oc + CC1;             // 256..511
        const uint64_t* wa = w1b + (size_t)oc  * 4;
        const uint64_t* wb = w1b + (size_t)oc2 * 4;
        int pa = 0, pb = 0;
        #pragma unroll
        for (int k = 0; k < 4; ++k) pa += popc64(hw[k] ^ wa[k]);
        #pragma unroll
        for (int k = 0; k < 4; ++k) pb += popc64(hw[k] ^ wb[k]);
        float hc = bf2f(hbuf[((size_t)(b * CC1 + oc)) * NPIX + p]);
        float za = (float)(256 - 2 * pa) * sc1[oc]  + bi1[oc]  + hc;
        float zb = (float)(256 - 2 * pb) * sc1[oc2] + bi1[oc2] + hc;
        out[((size_t)(b * CC2 + oc))  * NPIX + p] = za;
        out[((size_t)(b * CC2 + oc2)) * NPIX + p] = zb;
    }
}

extern "C" void kernel_launch(void* const* d_in, const int* in_sizes, int n_in,
                              void* d_out, int out_size, void* d_ws, size_t ws_size,
                              hipStream_t stream) {
    const float* x  = (const float*)d_in[0];
    const float* w3 = (const float*)d_in[1];
    const float* g3 = (const float*)d_in[2];
    const float* b3 = (const float*)d_in[3];
    const float* m3 = (const float*)d_in[4];
    const float* v3 = (const float*)d_in[5];
    const float* w1 = (const float*)d_in[6];
    const float* g1 = (const float*)d_in[7];
    const float* b1 = (const float*)d_in[8];
    const float* m1 = (const float*)d_in[9];
    const float* v1 = (const float*)d_in[10];
    float* out = (float*)d_out;

    uint8_t* ws = (uint8_t*)d_ws;
    size_t off = 0;
    uint64_t* xbp   = (uint64_t*)(ws + off); off += (size_t)BB * PH * PH * 4 * 8;   // 3,326,976
    uint64_t* hbits = (uint64_t*)(ws + off); off += (size_t)BB * NPIX * 4 * 8;      //   802,816
    uint64_t* w3t   = (uint64_t*)(ws + off); off += (size_t)9 * CC1 * 4 * 8;        //    73,728
    uint64_t* w1b   = (uint64_t*)(ws + off); off += (size_t)CC2 * 4 * 8;            //    16,384
    float* sc3 = (float*)(ws + off); off += CC1 * 4;
    float* bi3 = (float*)(ws + off); off += CC1 * 4;
    float* sc1 = (float*)(ws + off); off += CC2 * 4;
    float* bi1 = (float*)(ws + off); off += CC2 * 4;
    int* ctop  = (int*)(ws + off); off += CC1 * 4;
    int* cleft = (int*)(ws + off); off += CC1 * 4;
    int* ccorn = (int*)(ws + off); off += CC1 * 4;
    unsigned short* pool   = (unsigned short*)(ws + off); off += (size_t)BB * CC1 * NPIX * 2; // 12,845,056
    unsigned short* hbuf16 = (unsigned short*)(ws + off); off += (size_t)BB * CC1 * NPIX * 2; // 12,845,056

    k_binpool<<<dim3(100352 / 256), 256, 0, stream>>>(x, xbp, hbits, pool);
    k_packw3 <<<dim3(9216 / 256),   256, 0, stream>>>(w3, w3t);
    k_prep2  <<<dim3(2048 / 256),   256, 0, stream>>>(w1, w1b, w3t, g3, b3, m3, v3,
                                                      g1, b1, m1, v1, sc3, bi3, sc1, bi1,
                                                      ctop, cleft, ccorn);
    k_conv3  <<<dim3(98, 32), 256, 0, stream>>>(xbp, w3t, sc3, bi3, ctop, cleft, ccorn,
                                                pool, hbuf16, hbits);
    k_conv1  <<<dim3(98, 32), 256, 0, stream>>>(hbits, w1b, hbuf16, sc1, bi1, out);
}